// Round 3
// baseline (4750.761 us; speedup 1.0000x reference)
//
#include <hip/hip_runtime.h>

// DependencyParser: 2× two-layer BiLSTM (word E=512, pos P=128), T=1024, B=1,
// then rank-1 edge scores S[i][j] = H[i]@w1 + H[j]@w2 + b, diag=0.
//
// R3 changes vs R2 (R2: 3453 us, rec_kernel 2x1620 us, latency-bound):
//  - word fwd+bwd chains FUSED into one WG (32 WGs total): each poll's
//    producer stored a full step earlier -> cross-XCD round trip hidden.
//  - 2 barriers per fused step (was 2 per chain-step = 4).
//  - pollers = waves 4-7 (disjoint from nonlin wave 0).
//  - nonlinearity parallel across 32 lanes (0-15 fwd, 16-31 bwd).
//  - xg loads software-pipelined one step ahead.

#define T_LEN 1024

// ---------------------------------------------------------------- poison ----
__global__ void poison_kernel(unsigned* p, int n) {
  int i = blockIdx.x * blockDim.x + threadIdx.x;
  int stride = gridDim.x * blockDim.x;
  for (; i < n; i += stride) p[i] = 0xFFFFFFFFu;
}

// ------------------------------------------------ GEMM C = A@W^T + b0 + b1 ----
// A: [M][K], W: [2][N][K] (z = direction), C: [2][M][N]. 64x64 tile, 256 thr.
__global__ __launch_bounds__(256) void gemm_bt(
    const float* __restrict__ A,
    const float* __restrict__ Wt,
    const float* __restrict__ B0,
    const float* __restrict__ B1,
    float* __restrict__ C,
    int M, int N, int K)
{
  const int z = blockIdx.z;
  const float* W  = Wt + (size_t)z * N * K;
  const float* b0 = B0 + (size_t)z * N;
  const float* b1 = B1 + (size_t)z * N;
  float* Cz = C + (size_t)z * M * N;

  __shared__ __align__(16) float As[16][64];
  __shared__ __align__(16) float Ws[16][64];

  const int tid = threadIdx.x;
  const int tx = tid & 15, ty = tid >> 4;
  const int brow = blockIdx.y * 64, bcol = blockIdx.x * 64;
  const int lr = tid >> 2;          // 0..63
  const int lk = (tid & 3) << 2;    // 0,4,8,12

  float acc[4][4] = {};

  for (int k0 = 0; k0 < K; k0 += 16) {
    float4 av = *(const float4*)(A + (size_t)(brow + lr) * K + k0 + lk);
    float4 wv = *(const float4*)(W + (size_t)(bcol + lr) * K + k0 + lk);
    __syncthreads();
    As[lk + 0][lr] = av.x; As[lk + 1][lr] = av.y;
    As[lk + 2][lr] = av.z; As[lk + 3][lr] = av.w;
    Ws[lk + 0][lr] = wv.x; Ws[lk + 1][lr] = wv.y;
    Ws[lk + 2][lr] = wv.z; Ws[lk + 3][lr] = wv.w;
    __syncthreads();
    #pragma unroll
    for (int kk = 0; kk < 16; ++kk) {
      float4 a = *(const float4*)&As[kk][ty << 2];
      float4 w = *(const float4*)&Ws[kk][tx << 2];
      float a4[4] = {a.x, a.y, a.z, a.w};
      float w4[4] = {w.x, w.y, w.z, w.w};
      #pragma unroll
      for (int i = 0; i < 4; ++i)
        #pragma unroll
        for (int j = 0; j < 4; ++j)
          acc[i][j] = fmaf(a4[i], w4[j], acc[i][j]);
    }
  }

  const int nb = bcol + (tx << 2);
  float bias[4];
  #pragma unroll
  for (int j = 0; j < 4; ++j) bias[j] = b0[nb + j] + b1[nb + j];
  #pragma unroll
  for (int i = 0; i < 4; ++i) {
    int m = brow + (ty << 2) + i;
    float4 out;
    out.x = acc[i][0] + bias[0];
    out.y = acc[i][1] + bias[1];
    out.z = acc[i][2] + bias[2];
    out.w = acc[i][3] + bias[3];
    *(float4*)(Cz + (size_t)m * N + nb) = out;
  }
}

// --------------------------------------------------------- fast activations ----
__device__ __forceinline__ float fsigmoid(float x) {
  return 1.f / (1.f + __expf(-x));
}
__device__ __forceinline__ float ftanh(float x) {
  return 2.f / (1.f + __expf(-2.f * x)) - 1.f;
}

__device__ __forceinline__ bool hpoison(unsigned long long u) {
  return ((unsigned)u == 0xFFFFFFFFu) || ((unsigned)(u >> 32) == 0xFFFFFFFFu);
}

// ------------------------------------------- word LSTM, fwd+bwd fused per WG ----
// 32 WGs x 512 thr. WG owns h elems [wg*16, wg*16+16) of BOTH directions
// (64 gate rows each). Thread: r = tid>>3 gate row, p = tid&7 column part,
// wf[64] + wb[64] in VGPRs. h published as fp32 via agent-scope stores into
// 0xFFFFFFFF-poisoned buffers; waves 4-7 poll one 8B granule per chain
// (data-as-flag: h = sigmoid*tanh is never NaN). Each poll's producer stored
// one full fused step earlier -> round trip hidden under the other chain.
__device__ __forceinline__ void word_body(
    int wg,
    const float* __restrict__ xg_f, const float* __restrict__ xg_b,
    const float* __restrict__ whh_f, const float* __restrict__ whh_b,
    float* hbuf_f, float* hbuf_b)
{
  const int tid  = threadIdx.x;
  const int r    = tid >> 3;         // 0..63 gate row within WG
  const int p    = tid & 7;          // column part
  const int gate = r >> 4;
  const int elem = r & 15;
  const int grow = gate * 512 + wg * 16 + elem;

  __shared__ __align__(16) float h_f[8][68];     // part-major, 68 = bank stagger
  __shared__ __align__(16) float h_b[8][68];
  __shared__ float gatesF[64];
  __shared__ float gatesB[64];

  float wf[64], wb[64];
  #pragma unroll
  for (int c = 0; c < 64; ++c) {
    wf[c] = whh_f[(size_t)grow * 512 + p * 64 + c];
    wb[c] = whh_b[(size_t)grow * 512 + p * 64 + c];
  }

  float cst = 0.f;   // wave0: lanes 0-15 fwd cstate, lanes 16-31 bwd cstate
  unsigned long long* f64p = (unsigned long long*)hbuf_f;
  unsigned long long* b64p = (unsigned long long*)hbuf_b;
  unsigned* f32p = (unsigned*)hbuf_f;
  unsigned* b32p = (unsigned*)hbuf_b;

  // software-pipelined xg (only p==0 lanes use it)
  float xgf = 0.f, xgb = 0.f;
  if (p == 0) {
    xgf = xg_f[grow];                                   // t = 0
    xgb = xg_b[(size_t)(T_LEN - 1) * 2048 + grow];      // t = T-1
  }

  for (int s = 0; s < T_LEN; ++s) {
    const int t  = s;
    const int tb = T_LEN - 1 - s;

    // ---- stage h_prev (waves 4-7; 8B fwd + 8B bwd per thread) ----
    if (tid >= 256) {
      const int g  = tid - 256;      // 0..255 granule
      const int f0 = g << 1;
      float v0, v1, u0, u1;
      if (s == 0) {
        v0 = v1 = u0 = u1 = 0.f;
      } else {
        unsigned long long uf = __hip_atomic_load(
            f64p + (size_t)(s - 1) * 256 + g,
            __ATOMIC_RELAXED, __HIP_MEMORY_SCOPE_AGENT);
        unsigned long long ub = __hip_atomic_load(
            b64p + (size_t)(T_LEN - s) * 256 + g,
            __ATOMIC_RELAXED, __HIP_MEMORY_SCOPE_AGENT);
        while (hpoison(uf))
          uf = __hip_atomic_load(f64p + (size_t)(s - 1) * 256 + g,
                                 __ATOMIC_RELAXED, __HIP_MEMORY_SCOPE_AGENT);
        while (hpoison(ub))
          ub = __hip_atomic_load(b64p + (size_t)(T_LEN - s) * 256 + g,
                                 __ATOMIC_RELAXED, __HIP_MEMORY_SCOPE_AGENT);
        v0 = __uint_as_float((unsigned)uf);
        v1 = __uint_as_float((unsigned)(uf >> 32));
        u0 = __uint_as_float((unsigned)ub);
        u1 = __uint_as_float((unsigned)(ub >> 32));
      }
      h_f[f0 >> 6][f0 & 63] = v0;
      h_f[(f0 + 1) >> 6][(f0 + 1) & 63] = v1;
      h_b[f0 >> 6][f0 & 63] = u0;
      h_b[(f0 + 1) >> 6][(f0 + 1) & 63] = u1;
    }
    __syncthreads();   // B1: h_lds ready; prev-step gates consumers done

    // prefetch next step's xg (overlaps matvec)
    float xgf_n = 0.f, xgb_n = 0.f;
    if (p == 0 && s + 1 < T_LEN) {
      xgf_n = xg_f[(size_t)(s + 1) * 2048 + grow];
      xgb_n = xg_b[(size_t)(T_LEN - 2 - s) * 2048 + grow];
    }

    // ---- both matvecs ----
    const float4* hf4 = (const float4*)&h_f[p][0];
    const float4* hb4 = (const float4*)&h_b[p][0];
    float fa0 = 0.f, fa1 = 0.f, fa2 = 0.f, fa3 = 0.f;
    float ba0 = 0.f, ba1 = 0.f, ba2 = 0.f, ba3 = 0.f;
    #pragma unroll
    for (int c4 = 0; c4 < 16; ++c4) {
      float4 hv = hf4[c4];
      float4 kv = hb4[c4];
      fa0 = fmaf(wf[4 * c4 + 0], hv.x, fa0);
      fa1 = fmaf(wf[4 * c4 + 1], hv.y, fa1);
      fa2 = fmaf(wf[4 * c4 + 2], hv.z, fa2);
      fa3 = fmaf(wf[4 * c4 + 3], hv.w, fa3);
      ba0 = fmaf(wb[4 * c4 + 0], kv.x, ba0);
      ba1 = fmaf(wb[4 * c4 + 1], kv.y, ba1);
      ba2 = fmaf(wb[4 * c4 + 2], kv.z, ba2);
      ba3 = fmaf(wb[4 * c4 + 3], kv.w, ba3);
    }
    float accf = (fa0 + fa1) + (fa2 + fa3);
    float accb = (ba0 + ba1) + (ba2 + ba3);
    accf += __shfl_xor(accf, 1, 64);
    accb += __shfl_xor(accb, 1, 64);
    accf += __shfl_xor(accf, 2, 64);
    accb += __shfl_xor(accb, 2, 64);
    accf += __shfl_xor(accf, 4, 64);
    accb += __shfl_xor(accb, 4, 64);
    if (p == 0) {
      gatesF[r] = accf + xgf;
      gatesB[r] = accb + xgb;
    }
    __syncthreads();   // B2: gates ready

    // ---- nonlinearity + publish (wave 0, lanes 0-31) ----
    if (tid < 32) {
      const bool isB = tid >= 16;
      const int  e   = tid & 15;
      const float* gb = isB ? gatesB : gatesF;
      float gi = gb[e];
      float gf = gb[16 + e];
      float gg = gb[32 + e];
      float go = gb[48 + e];
      float si = fsigmoid(gi);
      float sf = fsigmoid(gf);
      float tg = ftanh(gg);
      float so = fsigmoid(go);
      cst = fmaf(sf, cst, si * tg);
      float h = so * ftanh(cst);
      if (!isB)
        __hip_atomic_store(f32p + (size_t)t * 512 + wg * 16 + e,
                           __float_as_uint(h),
                           __ATOMIC_RELAXED, __HIP_MEMORY_SCOPE_AGENT);
      else
        __hip_atomic_store(b32p + (size_t)tb * 512 + wg * 16 + e,
                           __float_as_uint(h),
                           __ATOMIC_RELAXED, __HIP_MEMORY_SCOPE_AGENT);
    }
    xgf = xgf_n;
    xgb = xgb_n;
    // no trailing barrier: next-step stagers write h_lds (not gates), and
    // next matvec's gates write happens only after B1.
  }
}

// ---------------------------------------------------- pos LSTM (single WG) ----
// H=128: one 512-thr WG per direction. Thread owns 1 gate row (w[128]).
// h lives in LDS; no cross-WG sync, plain global stores of the h history.
__device__ __forceinline__ void pos_body(
    const float* __restrict__ xg, const float* __restrict__ whh,
    float* __restrict__ hbuf, int rev)
{
  const int tid = threadIdx.x;       // gate row 0..511

  __shared__ __align__(16) float h_lds[128];
  __shared__ float gates[512];

  float w[128];
  #pragma unroll
  for (int c = 0; c < 128; ++c)
    w[c] = whh[(size_t)tid * 128 + c];

  float cstate = 0.f;                // valid for tid < 128

  for (int s = 0; s < T_LEN; ++s) {
    const int t = rev ? (T_LEN - 1 - s) : s;
    const float xgv = xg[(size_t)t * 512 + tid];

    if (s == 0 && tid < 128) h_lds[tid] = 0.f;
    __syncthreads();                 // prev nonlin h_lds writes -> this matvec

    const float4* h4 = (const float4*)&h_lds[0];
    float a0 = 0.f, a1 = 0.f, a2 = 0.f, a3 = 0.f;
    #pragma unroll
    for (int c4 = 0; c4 < 32; ++c4) {
      float4 hv = h4[c4];            // broadcast: all lanes same address
      a0 = fmaf(w[4 * c4 + 0], hv.x, a0);
      a1 = fmaf(w[4 * c4 + 1], hv.y, a1);
      a2 = fmaf(w[4 * c4 + 2], hv.z, a2);
      a3 = fmaf(w[4 * c4 + 3], hv.w, a3);
    }
    gates[tid] = ((a0 + a1) + (a2 + a3)) + xgv;
    __syncthreads();

    if (tid < 128) {
      float si = fsigmoid(gates[tid]);
      float sf = fsigmoid(gates[128 + tid]);
      float tg = ftanh(gates[256 + tid]);
      float so = fsigmoid(gates[384 + tid]);
      cstate = fmaf(sf, cstate, si * tg);
      float h = so * ftanh(cstate);
      h_lds[tid] = h;
      hbuf[(size_t)t * 128 + tid] = h;
    }
  }
}

__global__ __launch_bounds__(512, 1) void rec_kernel(
    const float* xg_wf, const float* xg_wb, const float* whh_w,
    float* h_wf, float* h_wb,
    const float* xg_pf, const float* xg_pb, const float* whh_p,
    float* h_pf, float* h_pb)
{
  int b = blockIdx.x;
  if (b < 32)
    word_body(b, xg_wf, xg_wb, whh_w, whh_w + 2048 * 512, h_wf, h_wb);
  else if (b == 32)
    pos_body(xg_pf, whh_p, h_pf, 0);
  else
    pos_body(xg_pb, whh_p + 512 * 128, h_pb, 1);
}

// ------------------------------------------------------------------ concat ----
__global__ void concat_k(const float* __restrict__ wf, const float* __restrict__ wb,
                         const float* __restrict__ pf, const float* __restrict__ pb,
                         float* __restrict__ wcat, float* __restrict__ pcat)
{
  const int totw = T_LEN * 1024;
  const int totp = T_LEN * 256;
  int idx = blockIdx.x * blockDim.x + threadIdx.x;
  int stride = gridDim.x * blockDim.x;
  for (int e = idx; e < totw + totp; e += stride) {
    if (e < totw) {
      int t = e >> 10, d = e & 1023;
      wcat[e] = d < 512 ? wf[t * 512 + d] : wb[t * 512 + (d - 512)];
    } else {
      int e2 = e - totw;
      int t = e2 >> 8, d = e2 & 255;
      pcat[e2] = d < 128 ? pf[t * 128 + d] : pb[t * 128 + (d - 128)];
    }
  }
}

// ------------------------------------------------------------- edge scores ----
__global__ __launch_bounds__(256) void edge_s(
    const float* __restrict__ hwf, const float* __restrict__ hwb,
    const float* __restrict__ hpf, const float* __restrict__ hpb,
    const float* __restrict__ ew, float* s1, float* s2)
{
  const int i = blockIdx.x;
  const int tid = threadIdx.x;
  float a1 = 0.f, a2 = 0.f;
  for (int d = tid; d < 1280; d += 256) {
    float hv;
    if (d < 512)       hv = hwf[i * 512 + d];
    else if (d < 1024) hv = hwb[i * 512 + d - 512];
    else if (d < 1152) hv = hpf[i * 128 + d - 1024];
    else               hv = hpb[i * 128 + d - 1152];
    a1 = fmaf(hv, ew[d], a1);
    a2 = fmaf(hv, ew[1280 + d], a2);
  }
  #pragma unroll
  for (int off = 32; off > 0; off >>= 1) {
    a1 += __shfl_xor(a1, off, 64);
    a2 += __shfl_xor(a2, off, 64);
  }
  __shared__ float r1[4], r2[4];
  const int wid = tid >> 6;
  if ((tid & 63) == 0) { r1[wid] = a1; r2[wid] = a2; }
  __syncthreads();
  if (tid == 0) {
    s1[i] = (r1[0] + r1[1]) + (r1[2] + r1[3]);
    s2[i] = (r2[0] + r2[1]) + (r2[2] + r2[3]);
  }
}

__global__ __launch_bounds__(256) void sfill(
    const float* __restrict__ s1, const float* __restrict__ s2,
    const float* __restrict__ eb, float* __restrict__ out)
{
  int e = blockIdx.x * 256 + threadIdx.x;  // 0 .. 1024*1024-1
  int i = e >> 10, j = e & 1023;
  out[e] = (i == j) ? 0.f : s1[i] + s2[j] + eb[0];
}

// ------------------------------------------------------------------ launch ----
extern "C" void kernel_launch(void* const* d_in, const int* in_sizes, int n_in,
                              void* d_out, int out_size, void* d_ws, size_t ws_size,
                              hipStream_t stream)
{
  const float* words   = (const float*)d_in[0];
  const float* pos     = (const float*)d_in[1];
  const float* w_w0_ih = (const float*)d_in[2];
  const float* w_w0_hh = (const float*)d_in[3];
  const float* w_b0_ih = (const float*)d_in[4];
  const float* w_b0_hh = (const float*)d_in[5];
  const float* w_w1_ih = (const float*)d_in[6];
  const float* w_w1_hh = (const float*)d_in[7];
  const float* w_b1_ih = (const float*)d_in[8];
  const float* w_b1_hh = (const float*)d_in[9];
  const float* p_w0_ih = (const float*)d_in[10];
  const float* p_w0_hh = (const float*)d_in[11];
  const float* p_b0_ih = (const float*)d_in[12];
  const float* p_b0_hh = (const float*)d_in[13];
  const float* p_w1_ih = (const float*)d_in[14];
  const float* p_w1_hh = (const float*)d_in[15];
  const float* p_b1_ih = (const float*)d_in[16];
  const float* p_b1_hh = (const float*)d_in[17];
  const float* edge_w  = (const float*)d_in[18];
  const float* edge_b  = (const float*)d_in[19];

  float* ws = (float*)d_ws;
  float* xg_w  = ws;                       // [2][1024][2048] = 4,194,304
  float* xg_p  = ws + 4194304;             // [2][1024][512]  = 1,048,576
  float* hw0_f = ws + 5242880;             // [1024][512] each (word: poisoned)
  float* hw0_b = hw0_f + 524288;
  float* hw1_f = hw0_b + 524288;
  float* hw1_b = hw1_f + 524288;
  float* hp0_f = hw1_b + 524288;           // [1024][128] each (pos: plain)
  float* hp0_b = hp0_f + 131072;
  float* hp1_f = hp0_b + 131072;
  float* hp1_b = hp1_f + 131072;
  float* wcat  = hp1_b + 131072;           // [1024][1024]
  float* pcat  = wcat + 1048576;           // [1024][256]
  float* s1    = pcat + 262144;
  float* s2    = s1 + 1024;

  // 1. poison the 4 word h buffers (data-as-flag sync); every call, since the
  //    harness does not re-poison between graph replays.
  poison_kernel<<<1024, 256, 0, stream>>>((unsigned*)hw0_f, 2097152);

  // 2. layer-0 input projections
  gemm_bt<<<dim3(32, 16, 2), 256, 0, stream>>>(words, w_w0_ih, w_b0_ih, w_b0_hh,
                                               xg_w, 1024, 2048, 512);
  gemm_bt<<<dim3(8, 16, 2), 256, 0, stream>>>(pos, p_w0_ih, p_b0_ih, p_b0_hh,
                                              xg_p, 1024, 512, 128);

  // 3. layer-0 recurrence (word fused f+b: 32 WGs, pos f/b: 2 WGs)
  rec_kernel<<<34, 512, 0, stream>>>(xg_w, xg_w + 2097152, w_w0_hh, hw0_f, hw0_b,
                                     xg_p, xg_p + 524288, p_w0_hh, hp0_f, hp0_b);

  // 4. concat layer-0 outputs
  concat_k<<<2048, 256, 0, stream>>>(hw0_f, hw0_b, hp0_f, hp0_b, wcat, pcat);

  // 5. layer-1 input projections (xg buffers reused)
  gemm_bt<<<dim3(32, 16, 2), 256, 0, stream>>>(wcat, w_w1_ih, w_b1_ih, w_b1_hh,
                                               xg_w, 1024, 2048, 1024);
  gemm_bt<<<dim3(8, 16, 2), 256, 0, stream>>>(pcat, p_w1_ih, p_b1_ih, p_b1_hh,
                                              xg_p, 1024, 512, 256);

  // 6. layer-1 recurrence
  rec_kernel<<<34, 512, 0, stream>>>(xg_w, xg_w + 2097152, w_w1_hh, hw1_f, hw1_b,
                                     xg_p, xg_p + 524288, p_w1_hh, hp1_f, hp1_b);

  // 7. edge scores
  edge_s<<<1024, 256, 0, stream>>>(hw1_f, hw1_b, hp1_f, hp1_b, edge_w, s1, s2);
  sfill<<<4096, 256, 0, stream>>>(s1, s2, edge_b, (float*)d_out);
}